// Round 5
// baseline (314.967 us; speedup 1.0000x reference)
//
#include <hip/hip_runtime.h>

// GCN layer: h = x @ W_conv; conv = D^-1/2 (A+I) D^-1/2 h + b_conv; out = conv @ W_lin + b_lin
// N=50000, E=800000, in_c=256, hid=128.
// h and conv in bf16, SLICE-MAJOR [4][N][32] so each 32-col slice (3.2 MB) is L2-resident
// during its gather pass. csr entries are ushort (N < 65536) to halve scatter-write traffic.

#define N_NODES 50000
#define N_EDGES 800000
#define IN_C 256
#define HID 128
#define SCAN_BLOCKS ((N_NODES + 255) / 256)   // 196
#define GEMM_MBLK ((N_NODES + 63) / 64)       // 782

// workspace layout (bytes)
#define OFF_H    0UL          // [4][50000][32] bf16 = 12,800,000
#define OFF_CONV 12800000UL   // [4][50000][32] bf16 = 12,800,000
#define OFF_DEG  25600000UL   // 50000 i32
#define OFF_CNT  25800000UL   // 50000 i32
#define OFF_RP   26000000UL   // 50001 i32
#define OFF_DINV 26200064UL   // 50000 f32
#define OFF_CSR  26400064UL   // 800000 u16 = 1,600,000
#define OFF_BSUM 28000064UL   // 256 i32
#define OFF_WT1  28001088UL   // 128*256 bf16 (W_conv^T)
#define OFF_WT2  28066624UL   // 256*128 bf16 (W_lin^T)

typedef __attribute__((ext_vector_type(8))) short bf16x8;
typedef __attribute__((ext_vector_type(4))) float f32x4;

__device__ __forceinline__ ushort f2bf(float x) {
    unsigned u = __float_as_uint(x);
    u += 0x7fffu + ((u >> 16) & 1u);       // round-to-nearest-even
    return (ushort)(u >> 16);
}

__global__ void deg_kernel(const int* __restrict__ dst, int* __restrict__ deg, int e) {
    int i = blockIdx.x * blockDim.x + threadIdx.x;
    if (i < e) atomicAdd(&deg[dst[i]], 1);
}

__global__ __launch_bounds__(256) void scan_blocks_kernel(
    const int* __restrict__ deg, int* __restrict__ row_ptr,
    int* __restrict__ bsums, int n)
{
    __shared__ int tmp[256];
    int tid = threadIdx.x;
    int i = blockIdx.x * 256 + tid;
    int v = (i < n) ? deg[i] : 0;
    int orig = v;
    tmp[tid] = v;
    __syncthreads();
    #pragma unroll
    for (int off = 1; off < 256; off <<= 1) {
        int t = (tid >= off) ? tmp[tid - off] : 0;
        __syncthreads();
        tmp[tid] += t;
        __syncthreads();
    }
    if (i < n) row_ptr[i] = tmp[tid] - orig;
    if (tid == 255) bsums[blockIdx.x] = tmp[255];
}

__global__ __launch_bounds__(256) void scan_sums_kernel(int* __restrict__ bsums, int nb) {
    __shared__ int tmp[256];
    int tid = threadIdx.x;
    int v = (tid < nb) ? bsums[tid] : 0;
    int orig = v;
    tmp[tid] = v;
    __syncthreads();
    #pragma unroll
    for (int off = 1; off < 256; off <<= 1) {
        int t = (tid >= off) ? tmp[tid - off] : 0;
        __syncthreads();
        tmp[tid] += t;
        __syncthreads();
    }
    if (tid < nb) bsums[tid] = tmp[tid] - orig;
}

__global__ __launch_bounds__(256) void finalize_kernel(
    const int* __restrict__ deg, int* __restrict__ row_ptr,
    const int* __restrict__ bsums, float* __restrict__ dinv, int n)
{
    int i = blockIdx.x * 256 + threadIdx.x;
    if (i < n) {
        row_ptr[i] += bsums[blockIdx.x];
        dinv[i] = rsqrtf((float)(deg[i] + 1));
    }
    if (i == 0) row_ptr[n] = N_EDGES;
}

__global__ void bucket_kernel(const int* __restrict__ src, const int* __restrict__ dst,
                              const int* __restrict__ row_ptr, int* __restrict__ cnt,
                              ushort* __restrict__ csr_src, int e) {
    int i = blockIdx.x * blockDim.x + threadIdx.x;
    if (i < e) {
        int d = dst[i];
        int slot = row_ptr[d] + atomicAdd(&cnt[d], 1);
        csr_src[slot] = (ushort)src[i];
    }
}

// W [K][N] fp32 -> Wt [N][K] bf16
__global__ void transpose_w_kernel(const float* __restrict__ W, ushort* __restrict__ Wt,
                                   int K, int N) {
    int i = blockIdx.x * 256 + threadIdx.x;
    if (i < N * K) {
        int n = i / K, k = i % K;
        Wt[i] = f2bf(W[k * N + n]);
    }
}

// C[M,N] = A[M,K] @ B[K,N] (+bias) via bf16 MFMA 16x16x32.
// A_SLICED: A is bf16 slice-major [K/32][M][32]; else fp32 row-major (converted in staging).
// OUT_SLICED: C written as bf16 slice-major [N/32][M][32]; else fp32 row-major.
// BM=64, BN=128, BK=32; 256 threads = 4 waves 2x2; wave tile 32x64.
template <bool A_SLICED, bool OUT_SLICED>
__global__ __launch_bounds__(256) void mfma_gemm_kernel(
    const void* __restrict__ Av, const ushort* __restrict__ Bt,
    const float* __restrict__ bias, void* __restrict__ Cv,
    int M, int N, int K)
{
    constexpr int LDK = 40;
    __shared__ ushort As[64 * LDK];
    __shared__ ushort Bs[128 * LDK];
    int tid = threadIdx.x;
    int wave = tid >> 6, lane = tid & 63;
    int quad = lane >> 4, l16 = lane & 15;
    int wm0 = (wave >> 1) * 32, wn0 = (wave & 1) * 64;
    int bm = blockIdx.x * 64, bn = blockIdx.y * 128;

    f32x4 acc[2][4] = {};

    for (int k0 = 0; k0 < K; k0 += 32) {
        // ---- stage A tile (64 x 32) ----
        {
            int row = tid >> 2, col = (tid & 3) * 8;
            int grow = bm + row;
            if (A_SLICED) {
                bf16x8 v = {};
                if (grow < M)
                    v = *(const bf16x8*)((const ushort*)Av +
                          ((size_t)(k0 >> 5) * M + grow) * 32 + col);
                *(bf16x8*)&As[row * LDK + col] = v;
            } else {
                float4 v0 = make_float4(0.f, 0.f, 0.f, 0.f);
                float4 v1 = make_float4(0.f, 0.f, 0.f, 0.f);
                if (grow < M) {
                    const float* ap = (const float*)Av + (size_t)grow * K + k0 + col;
                    v0 = *(const float4*)ap;
                    v1 = *(const float4*)(ap + 4);
                }
                ushort t[8] = {f2bf(v0.x), f2bf(v0.y), f2bf(v0.z), f2bf(v0.w),
                               f2bf(v1.x), f2bf(v1.y), f2bf(v1.z), f2bf(v1.w)};
                *(bf16x8*)&As[row * LDK + col] = *(bf16x8*)t;
            }
        }
        // ---- stage B tile (128 x 32) from Bt rows (contiguous k) ----
        {
            int ch = tid * 2;
            int n = ch >> 2;
            int kk = (ch & 3) * 8;
            const ushort* bp = Bt + (size_t)(bn + n) * K + k0 + kk;
            *(bf16x8*)&Bs[n * LDK + kk]     = *(const bf16x8*)bp;
            *(bf16x8*)&Bs[n * LDK + kk + 8] = *(const bf16x8*)(bp + 8);
        }
        __syncthreads();
        bf16x8 af[2], bfr[4];
        #pragma unroll
        for (int im = 0; im < 2; ++im)
            af[im] = *(bf16x8*)&As[(wm0 + im * 16 + l16) * LDK + quad * 8];
        #pragma unroll
        for (int in = 0; in < 4; ++in)
            bfr[in] = *(bf16x8*)&Bs[(wn0 + in * 16 + l16) * LDK + quad * 8];
        #pragma unroll
        for (int im = 0; im < 2; ++im)
            #pragma unroll
            for (int in = 0; in < 4; ++in)
                acc[im][in] = __builtin_amdgcn_mfma_f32_16x16x32_bf16(
                    af[im], bfr[in], acc[im][in], 0, 0, 0);
        __syncthreads();
    }
    // ---- epilogue: C/D layout col=lane&15, row=quad*4+reg ----
    #pragma unroll
    for (int im = 0; im < 2; ++im) {
        #pragma unroll
        for (int in = 0; in < 4; ++in) {
            int col = bn + wn0 + in * 16 + l16;
            float bval = bias ? bias[col] : 0.f;
            #pragma unroll
            for (int r = 0; r < 4; ++r) {
                int grow = bm + wm0 + im * 16 + quad * 4 + r;
                if (grow < M) {
                    float o = acc[im][in][r] + bval;
                    if (OUT_SLICED)
                        ((ushort*)Cv)[((size_t)(col >> 5) * M + grow) * 32 + (col & 31)] = f2bf(o);
                    else
                        ((float*)Cv)[(size_t)grow * N + col] = o;
                }
            }
        }
    }
}

// Per (node, 32-col slice): conv_s[slice][d][:] = bf16( di*(sum_in dinv[s]*h_s[slice][s][:]
//   + di*h_s[slice][d][:]) + b_conv[slice*32..] )
// grid=(ceil(N/4), 4 slices slow) so each 3.2MB slice is L2-resident during its pass.
// wave64 per node-slice: 16 lanes per edge (4B = 2 cols each), 4 edges in flight.
__global__ __launch_bounds__(256) void gather_kernel(
    const ushort* __restrict__ hb, const int* __restrict__ row_ptr,
    const ushort* __restrict__ csr_src, const float* __restrict__ dinv,
    const float* __restrict__ b_conv, ushort* __restrict__ convb, int n)
{
    int wave = threadIdx.x >> 6;
    int lane = threadIdx.x & 63;
    int d = blockIdx.x * 4 + wave;
    if (d >= n) return;
    int slice = blockIdx.y;
    int sub = lane >> 4;        // which of 4 concurrent edges
    int l16 = lane & 15;        // 2 cols per lane
    const ushort* hsl = hb + (size_t)slice * N_NODES * 32;

    float2 acc = make_float2(0.f, 0.f);
    int begin = row_ptr[d], end = row_ptr[d + 1];
    for (int e = begin + sub; e < end; e += 4) {
        int s = csr_src[e];
        float w = dinv[s];
        unsigned v = *(const unsigned*)&hsl[(size_t)s * 32 + l16 * 2];
        acc.x += w * __uint_as_float(v << 16);
        acc.y += w * __uint_as_float(v & 0xffff0000u);
    }
    // reduce the 4 sub-accumulators (lane bits 4,5)
    acc.x += __shfl_xor(acc.x, 16); acc.y += __shfl_xor(acc.y, 16);
    acc.x += __shfl_xor(acc.x, 32); acc.y += __shfl_xor(acc.y, 32);

    if (sub == 0) {
        float di = dinv[d];
        unsigned hv = *(const unsigned*)&hsl[(size_t)d * 32 + l16 * 2];
        acc.x += di * __uint_as_float(hv << 16);
        acc.y += di * __uint_as_float(hv & 0xffff0000u);
        int c = slice * 32 + l16 * 2;
        float ox = di * acc.x + b_conv[c];
        float oy = di * acc.y + b_conv[c + 1];
        unsigned po = ((unsigned)f2bf(oy) << 16) | (unsigned)f2bf(ox);
        *(unsigned*)&convb[((size_t)slice * N_NODES + d) * 32 + l16 * 2] = po;
    }
}

extern "C" void kernel_launch(void* const* d_in, const int* in_sizes, int n_in,
                              void* d_out, int out_size, void* d_ws, size_t ws_size,
                              hipStream_t stream) {
    const float* x      = (const float*)d_in[0];
    const int*   ei     = (const int*)d_in[1];
    const float* W_conv = (const float*)d_in[2];
    const float* b_conv = (const float*)d_in[3];
    const float* W_lin  = (const float*)d_in[4];
    const float* b_lin  = (const float*)d_in[5];
    float* out = (float*)d_out;

    char* ws = (char*)d_ws;
    ushort* hb     = (ushort*)(ws + OFF_H);
    ushort* convb  = (ushort*)(ws + OFF_CONV);
    int*   deg     = (int*)(ws + OFF_DEG);
    int*   cnt     = (int*)(ws + OFF_CNT);
    int*   row_ptr = (int*)(ws + OFF_RP);
    float* dinv    = (float*)(ws + OFF_DINV);
    ushort* csr_src = (ushort*)(ws + OFF_CSR);
    int*   bsums   = (int*)(ws + OFF_BSUM);
    ushort* wt_conv = (ushort*)(ws + OFF_WT1);
    ushort* wt_lin  = (ushort*)(ws + OFF_WT2);

    const int* src = ei;
    const int* dst = ei + N_EDGES;

    hipMemsetAsync(deg, 0, 400000, stream);  // deg + cnt contiguous

    deg_kernel<<<(N_EDGES + 255) / 256, 256, 0, stream>>>(dst, deg, N_EDGES);
    scan_blocks_kernel<<<SCAN_BLOCKS, 256, 0, stream>>>(deg, row_ptr, bsums, N_NODES);
    scan_sums_kernel<<<1, 256, 0, stream>>>(bsums, SCAN_BLOCKS);
    finalize_kernel<<<SCAN_BLOCKS, 256, 0, stream>>>(deg, row_ptr, bsums, dinv, N_NODES);
    bucket_kernel<<<(N_EDGES + 255) / 256, 256, 0, stream>>>(src, dst, row_ptr, cnt, csr_src, N_EDGES);

    transpose_w_kernel<<<(HID * IN_C + 255) / 256, 256, 0, stream>>>(W_conv, wt_conv, IN_C, HID);
    transpose_w_kernel<<<(IN_C * HID + 255) / 256, 256, 0, stream>>>(W_lin, wt_lin, HID, IN_C);

    // h = bf16(x @ W_conv), slice-major
    mfma_gemm_kernel<false, true><<<dim3(GEMM_MBLK, HID / 128), 256, 0, stream>>>(
        x, wt_conv, nullptr, hb, N_NODES, HID, IN_C);

    gather_kernel<<<dim3((N_NODES + 3) / 4, 4), 256, 0, stream>>>(
        hb, row_ptr, csr_src, dinv, b_conv, convb, N_NODES);

    // out = conv @ W_lin + b_lin (A slice-major bf16)
    mfma_gemm_kernel<true, false><<<dim3(GEMM_MBLK, IN_C / 128), 256, 0, stream>>>(
        convb, wt_lin, b_lin, out, N_NODES, IN_C, HID);
}

// Round 6
// 238.841 us; speedup vs baseline: 1.3187x; 1.3187x over previous
//
#include <hip/hip_runtime.h>
#include <hip/hip_fp16.h>

// GCN layer: h = x @ W_conv; conv = D^-1/2 (A+I) D^-1/2 h + b_conv; out = conv @ W_lin + b_lin
// N=50000, E=800000, in_c=256, hid=128.
// h, conv in bf16 row-major. CSR stored as packed u32 records (src u16 | fp16 weight).
// CSR fill is atomic-free (rank captured in deg pass) and XCD-class filtered so
// scatter writes to a given line merge in one XCD's L2.

#define N_NODES 50000
#define N_EDGES 800000
#define IN_C 256
#define HID 128
#define SCAN_BLOCKS ((N_NODES + 255) / 256)   // 196
#define GEMM_MBLK ((N_NODES + 63) / 64)       // 782

// workspace layout (bytes)
#define OFF_H    0UL          // [N][128] bf16 = 12,800,000
#define OFF_CONV 12800000UL   // [N][128] bf16 = 12,800,000
#define OFF_DEG  25600000UL   // 50000 i32
#define OFF_RP   25800000UL   // 50001 i32 (pad to 64)
#define OFF_DINV 26000064UL   // 50000 f32
#define OFF_RANK 26200064UL   // 800000 u16 = 1,600,000
#define OFF_REC  27800064UL   // 800000 u32 = 3,200,000
#define OFF_BSUM 31000064UL   // 256 i32
#define OFF_WT1  31001088UL   // 128*256 bf16 (W_conv^T)
#define OFF_WT2  31066624UL   // 256*128 bf16 (W_lin^T)

typedef __attribute__((ext_vector_type(8))) short bf16x8;
typedef __attribute__((ext_vector_type(4))) float f32x4;

__device__ __forceinline__ ushort f2bf(float x) {
    unsigned u = __float_as_uint(x);
    u += 0x7fffu + ((u >> 16) & 1u);       // round-to-nearest-even
    return (ushort)(u >> 16);
}

// deg count + per-edge rank within its dst bucket (atomicAdd old value)
__global__ void deg_kernel(const int* __restrict__ dst, int* __restrict__ deg,
                           ushort* __restrict__ rank, int e) {
    int i = blockIdx.x * blockDim.x + threadIdx.x;
    if (i < e) rank[i] = (ushort)atomicAdd(&deg[dst[i]], 1);
}

__global__ __launch_bounds__(256) void scan_blocks_kernel(
    const int* __restrict__ deg, int* __restrict__ row_ptr,
    int* __restrict__ bsums, int n)
{
    __shared__ int tmp[256];
    int tid = threadIdx.x;
    int i = blockIdx.x * 256 + tid;
    int v = (i < n) ? deg[i] : 0;
    int orig = v;
    tmp[tid] = v;
    __syncthreads();
    #pragma unroll
    for (int off = 1; off < 256; off <<= 1) {
        int t = (tid >= off) ? tmp[tid - off] : 0;
        __syncthreads();
        tmp[tid] += t;
        __syncthreads();
    }
    if (i < n) row_ptr[i] = tmp[tid] - orig;
    if (tid == 255) bsums[blockIdx.x] = tmp[255];
}

__global__ __launch_bounds__(256) void scan_sums_kernel(int* __restrict__ bsums, int nb) {
    __shared__ int tmp[256];
    int tid = threadIdx.x;
    int v = (tid < nb) ? bsums[tid] : 0;
    int orig = v;
    tmp[tid] = v;
    __syncthreads();
    #pragma unroll
    for (int off = 1; off < 256; off <<= 1) {
        int t = (tid >= off) ? tmp[tid - off] : 0;
        __syncthreads();
        tmp[tid] += t;
        __syncthreads();
    }
    if (tid < nb) bsums[tid] = tmp[tid] - orig;
}

__global__ __launch_bounds__(256) void finalize_kernel(
    const int* __restrict__ deg, int* __restrict__ row_ptr,
    const int* __restrict__ bsums, float* __restrict__ dinv, int n)
{
    int i = blockIdx.x * 256 + threadIdx.x;
    if (i < n) {
        row_ptr[i] += bsums[blockIdx.x];
        dinv[i] = rsqrtf((float)(deg[i] + 1));
    }
    if (i == 0) row_ptr[n] = N_EDGES;
}

// CSR fill, atomic-free. Blocks of XCD class c (= blockIdx%8) only handle dsts in
// range [c*6250, (c+1)*6250): all writes to a given rec-line come from one XCD's L2
// (dispatch round-robin heuristic; correctness does not depend on it).
// rec = src u16 | fp16(dinv[src]) << 16.
#define BUCKET_BLOCKS 2048
__global__ __launch_bounds__(256) void bucket_kernel(
    const int* __restrict__ src, const int* __restrict__ dst,
    const ushort* __restrict__ rank, const int* __restrict__ row_ptr,
    const float* __restrict__ dinv, unsigned* __restrict__ rec)
{
    int cls = blockIdx.x & 7;
    int blk = blockIdx.x >> 3;                 // 0..255
    int lo = cls * (N_NODES / 8);              // 6250 per class
    int hi = lo + (N_NODES / 8);
    const int CHUNK = (N_EDGES + 255) / 256;   // 3125
    int e0 = blk * CHUNK;
    int e1 = min(e0 + CHUNK, N_EDGES);
    for (int i = e0 + threadIdx.x; i < e1; i += 256) {
        int d = dst[i];
        if (d >= lo && d < hi) {
            int s = src[i];
            unsigned r = (unsigned)(ushort)s |
                         ((unsigned)__half_as_ushort(__float2half_rn(dinv[s])) << 16);
            rec[row_ptr[d] + rank[i]] = r;
        }
    }
}

// W [K][N] fp32 -> Wt [N][K] bf16
__global__ void transpose_w_kernel(const float* __restrict__ W, ushort* __restrict__ Wt,
                                   int K, int N) {
    int i = blockIdx.x * 256 + threadIdx.x;
    if (i < N * K) {
        int n = i / K, k = i % K;
        Wt[i] = f2bf(W[k * N + n]);
    }
}

// C[M,N] = A[M,K] @ B[K,N] (+bias) via bf16 MFMA 16x16x32.
// A row-major (fp32 or bf16); Bt = B^T bf16 row-major [N][K].
// BM=64, BN=128, BK=32; 256 threads = 4 waves 2x2; wave tile 32x64.
template <bool A_IS_BF16, bool BF16OUT>
__global__ __launch_bounds__(256) void mfma_gemm_kernel(
    const void* __restrict__ Av, const ushort* __restrict__ Bt,
    const float* __restrict__ bias, void* __restrict__ Cv,
    int M, int N, int K)
{
    constexpr int LDK = 40;
    __shared__ ushort As[64 * LDK];
    __shared__ ushort Bs[128 * LDK];
    int tid = threadIdx.x;
    int wave = tid >> 6, lane = tid & 63;
    int quad = lane >> 4, l16 = lane & 15;
    int wm0 = (wave >> 1) * 32, wn0 = (wave & 1) * 64;
    int bm = blockIdx.x * 64, bn = blockIdx.y * 128;

    f32x4 acc[2][4] = {};

    for (int k0 = 0; k0 < K; k0 += 32) {
        {
            int row = tid >> 2, col = (tid & 3) * 8;
            int grow = bm + row;
            if (A_IS_BF16) {
                bf16x8 v = {};
                if (grow < M)
                    v = *(const bf16x8*)((const ushort*)Av + (size_t)grow * K + k0 + col);
                *(bf16x8*)&As[row * LDK + col] = v;
            } else {
                float4 v0 = make_float4(0.f, 0.f, 0.f, 0.f);
                float4 v1 = make_float4(0.f, 0.f, 0.f, 0.f);
                if (grow < M) {
                    const float* ap = (const float*)Av + (size_t)grow * K + k0 + col;
                    v0 = *(const float4*)ap;
                    v1 = *(const float4*)(ap + 4);
                }
                ushort t[8] = {f2bf(v0.x), f2bf(v0.y), f2bf(v0.z), f2bf(v0.w),
                               f2bf(v1.x), f2bf(v1.y), f2bf(v1.z), f2bf(v1.w)};
                *(bf16x8*)&As[row * LDK + col] = *(bf16x8*)t;
            }
        }
        {
            int ch = tid * 2;
            int n = ch >> 2;
            int kk = (ch & 3) * 8;
            const ushort* bp = Bt + (size_t)(bn + n) * K + k0 + kk;
            *(bf16x8*)&Bs[n * LDK + kk]     = *(const bf16x8*)bp;
            *(bf16x8*)&Bs[n * LDK + kk + 8] = *(const bf16x8*)(bp + 8);
        }
        __syncthreads();
        bf16x8 af[2], bfr[4];
        #pragma unroll
        for (int im = 0; im < 2; ++im)
            af[im] = *(bf16x8*)&As[(wm0 + im * 16 + l16) * LDK + quad * 8];
        #pragma unroll
        for (int in = 0; in < 4; ++in)
            bfr[in] = *(bf16x8*)&Bs[(wn0 + in * 16 + l16) * LDK + quad * 8];
        #pragma unroll
        for (int im = 0; im < 2; ++im)
            #pragma unroll
            for (int in = 0; in < 4; ++in)
                acc[im][in] = __builtin_amdgcn_mfma_f32_16x16x32_bf16(
                    af[im], bfr[in], acc[im][in], 0, 0, 0);
        __syncthreads();
    }
    #pragma unroll
    for (int im = 0; im < 2; ++im) {
        #pragma unroll
        for (int in = 0; in < 4; ++in) {
            int col = bn + wn0 + in * 16 + l16;
            float bval = bias ? bias[col] : 0.f;
            #pragma unroll
            for (int r = 0; r < 4; ++r) {
                int grow = bm + wm0 + im * 16 + quad * 4 + r;
                if (grow < M) {
                    float o = acc[im][in][r] + bval;
                    if (BF16OUT)
                        ((ushort*)Cv)[(size_t)grow * N + col] = f2bf(o);
                    else
                        ((float*)Cv)[(size_t)grow * N + col] = o;
                }
            }
        }
    }
}

// convb[d][:] = bf16( di*( sum_in w_s*h[s][:] + di*h[d][:] ) + b_conv )
// wave64 per node; lane owns 2 cols (4B). One packed rec load per edge (s + fp16 w).
__global__ __launch_bounds__(256) void gather_kernel(
    const ushort* __restrict__ hb, const int* __restrict__ row_ptr,
    const unsigned* __restrict__ rec, const float* __restrict__ dinv,
    const float* __restrict__ b_conv, ushort* __restrict__ convb, int n)
{
    int wave = threadIdx.x >> 6;
    int lane = threadIdx.x & 63;
    int d = blockIdx.x * 4 + wave;
    if (d >= n) return;
    int c = lane << 1;
    float di = dinv[d];
    unsigned hv = *(const unsigned*)&hb[(size_t)d * HID + c];
    float2 acc;
    acc.x = di * __uint_as_float(hv << 16);
    acc.y = di * __uint_as_float(hv & 0xffff0000u);
    int begin = row_ptr[d], end = row_ptr[d + 1];
    int e = begin;
    for (; e + 4 <= end; e += 4) {
        unsigned r0 = rec[e], r1 = rec[e + 1], r2 = rec[e + 2], r3 = rec[e + 3];
        unsigned s0 = r0 & 0xffffu, s1 = r1 & 0xffffu, s2 = r2 & 0xffffu, s3 = r3 & 0xffffu;
        float w0 = __half2float(__ushort_as_half((ushort)(r0 >> 16)));
        float w1 = __half2float(__ushort_as_half((ushort)(r1 >> 16)));
        float w2 = __half2float(__ushort_as_half((ushort)(r2 >> 16)));
        float w3 = __half2float(__ushort_as_half((ushort)(r3 >> 16)));
        unsigned v0 = *(const unsigned*)&hb[(size_t)s0 * HID + c];
        unsigned v1 = *(const unsigned*)&hb[(size_t)s1 * HID + c];
        unsigned v2 = *(const unsigned*)&hb[(size_t)s2 * HID + c];
        unsigned v3 = *(const unsigned*)&hb[(size_t)s3 * HID + c];
        acc.x += w0 * __uint_as_float(v0 << 16);
        acc.y += w0 * __uint_as_float(v0 & 0xffff0000u);
        acc.x += w1 * __uint_as_float(v1 << 16);
        acc.y += w1 * __uint_as_float(v1 & 0xffff0000u);
        acc.x += w2 * __uint_as_float(v2 << 16);
        acc.y += w2 * __uint_as_float(v2 & 0xffff0000u);
        acc.x += w3 * __uint_as_float(v3 << 16);
        acc.y += w3 * __uint_as_float(v3 & 0xffff0000u);
    }
    for (; e < end; ++e) {
        unsigned r0 = rec[e];
        unsigned s0 = r0 & 0xffffu;
        float w0 = __half2float(__ushort_as_half((ushort)(r0 >> 16)));
        unsigned v0 = *(const unsigned*)&hb[(size_t)s0 * HID + c];
        acc.x += w0 * __uint_as_float(v0 << 16);
        acc.y += w0 * __uint_as_float(v0 & 0xffff0000u);
    }
    float ox = di * acc.x + b_conv[c];
    float oy = di * acc.y + b_conv[c + 1];
    unsigned po = ((unsigned)f2bf(oy) << 16) | (unsigned)f2bf(ox);
    *(unsigned*)&convb[(size_t)d * HID + c] = po;
}

extern "C" void kernel_launch(void* const* d_in, const int* in_sizes, int n_in,
                              void* d_out, int out_size, void* d_ws, size_t ws_size,
                              hipStream_t stream) {
    const float* x      = (const float*)d_in[0];
    const int*   ei     = (const int*)d_in[1];
    const float* W_conv = (const float*)d_in[2];
    const float* b_conv = (const float*)d_in[3];
    const float* W_lin  = (const float*)d_in[4];
    const float* b_lin  = (const float*)d_in[5];
    float* out = (float*)d_out;

    char* ws = (char*)d_ws;
    ushort* hb      = (ushort*)(ws + OFF_H);
    ushort* convb   = (ushort*)(ws + OFF_CONV);
    int*    deg     = (int*)(ws + OFF_DEG);
    int*    row_ptr = (int*)(ws + OFF_RP);
    float*  dinv    = (float*)(ws + OFF_DINV);
    ushort* rank    = (ushort*)(ws + OFF_RANK);
    unsigned* rec   = (unsigned*)(ws + OFF_REC);
    int*    bsums   = (int*)(ws + OFF_BSUM);
    ushort* wt_conv = (ushort*)(ws + OFF_WT1);
    ushort* wt_lin  = (ushort*)(ws + OFF_WT2);

    const int* src = ei;
    const int* dst = ei + N_EDGES;

    hipMemsetAsync(deg, 0, 200000, stream);

    deg_kernel<<<(N_EDGES + 255) / 256, 256, 0, stream>>>(dst, deg, rank, N_EDGES);
    scan_blocks_kernel<<<SCAN_BLOCKS, 256, 0, stream>>>(deg, row_ptr, bsums, N_NODES);
    scan_sums_kernel<<<1, 256, 0, stream>>>(bsums, SCAN_BLOCKS);
    finalize_kernel<<<SCAN_BLOCKS, 256, 0, stream>>>(deg, row_ptr, bsums, dinv, N_NODES);
    bucket_kernel<<<BUCKET_BLOCKS, 256, 0, stream>>>(src, dst, rank, row_ptr, dinv, rec);

    transpose_w_kernel<<<(HID * IN_C + 255) / 256, 256, 0, stream>>>(W_conv, wt_conv, IN_C, HID);
    transpose_w_kernel<<<(IN_C * HID + 255) / 256, 256, 0, stream>>>(W_lin, wt_lin, HID, IN_C);

    // h = bf16(x @ W_conv), row-major
    mfma_gemm_kernel<false, true><<<dim3(GEMM_MBLK, HID / 128), 256, 0, stream>>>(
        x, wt_conv, nullptr, hb, N_NODES, HID, IN_C);

    gather_kernel<<<(N_NODES + 3) / 4, 256, 0, stream>>>(
        hb, row_ptr, rec, dinv, b_conv, convb, N_NODES);

    // out = conv @ W_lin + b_lin
    mfma_gemm_kernel<true, false><<<dim3(GEMM_MBLK, IN_C / 128), 256, 0, stream>>>(
        convb, wt_lin, b_lin, out, N_NODES, IN_C, HID);
}

// Round 7
// 232.145 us; speedup vs baseline: 1.3568x; 1.0288x over previous
//
#include <hip/hip_runtime.h>
#include <hip/hip_fp16.h>

// GCN layer: h = x @ W_conv; conv = D^-1/2 (A+I) D^-1/2 h + b_conv; out = conv @ W_lin + b_lin
// N=50000, E=800000, in_c=256, hid=128.
// h, conv in bf16 row-major. CSR stored as packed u32 records (src u16 | fp16 weight).
// CSR fill is atomic-free (rank captured in deg pass) and XCD-class filtered.
// Gather: wave64 per node, two 32-lane halves process alternate edges with 8B loads,
// unroll 4 per half (8 h-loads in flight) — latency-bound, MLP is the lever.

#define N_NODES 50000
#define N_EDGES 800000
#define IN_C 256
#define HID 128
#define SCAN_BLOCKS ((N_NODES + 255) / 256)   // 196
#define GEMM_MBLK ((N_NODES + 63) / 64)       // 782

// workspace layout (bytes)
#define OFF_H    0UL          // [N][128] bf16 = 12,800,000
#define OFF_CONV 12800000UL   // [N][128] bf16 = 12,800,000
#define OFF_DEG  25600000UL   // 50000 i32
#define OFF_RP   25800000UL   // 50001 i32 (pad to 64)
#define OFF_DINV 26000064UL   // 50000 f32
#define OFF_RANK 26200064UL   // 800000 u16 = 1,600,000
#define OFF_REC  27800064UL   // 800000 u32 = 3,200,000
#define OFF_BSUM 31000064UL   // 256 i32
#define OFF_WT1  31001088UL   // 128*256 bf16 (W_conv^T)
#define OFF_WT2  31066624UL   // 256*128 bf16 (W_lin^T)

typedef __attribute__((ext_vector_type(8))) short bf16x8;
typedef __attribute__((ext_vector_type(4))) float f32x4;

__device__ __forceinline__ ushort f2bf(float x) {
    unsigned u = __float_as_uint(x);
    u += 0x7fffu + ((u >> 16) & 1u);       // round-to-nearest-even
    return (ushort)(u >> 16);
}

// deg count + per-edge rank within its dst bucket (atomicAdd old value)
__global__ void deg_kernel(const int* __restrict__ dst, int* __restrict__ deg,
                           ushort* __restrict__ rank, int e) {
    int i = blockIdx.x * blockDim.x + threadIdx.x;
    if (i < e) rank[i] = (ushort)atomicAdd(&deg[dst[i]], 1);
}

__global__ __launch_bounds__(256) void scan_blocks_kernel(
    const int* __restrict__ deg, int* __restrict__ row_ptr,
    int* __restrict__ bsums, int n)
{
    __shared__ int tmp[256];
    int tid = threadIdx.x;
    int i = blockIdx.x * 256 + tid;
    int v = (i < n) ? deg[i] : 0;
    int orig = v;
    tmp[tid] = v;
    __syncthreads();
    #pragma unroll
    for (int off = 1; off < 256; off <<= 1) {
        int t = (tid >= off) ? tmp[tid - off] : 0;
        __syncthreads();
        tmp[tid] += t;
        __syncthreads();
    }
    if (i < n) row_ptr[i] = tmp[tid] - orig;
    if (tid == 255) bsums[blockIdx.x] = tmp[255];
}

__global__ __launch_bounds__(256) void scan_sums_kernel(int* __restrict__ bsums, int nb) {
    __shared__ int tmp[256];
    int tid = threadIdx.x;
    int v = (tid < nb) ? bsums[tid] : 0;
    int orig = v;
    tmp[tid] = v;
    __syncthreads();
    #pragma unroll
    for (int off = 1; off < 256; off <<= 1) {
        int t = (tid >= off) ? tmp[tid - off] : 0;
        __syncthreads();
        tmp[tid] += t;
        __syncthreads();
    }
    if (tid < nb) bsums[tid] = tmp[tid] - orig;
}

__global__ __launch_bounds__(256) void finalize_kernel(
    const int* __restrict__ deg, int* __restrict__ row_ptr,
    const int* __restrict__ bsums, float* __restrict__ dinv, int n)
{
    int i = blockIdx.x * 256 + threadIdx.x;
    if (i < n) {
        row_ptr[i] += bsums[blockIdx.x];
        dinv[i] = rsqrtf((float)(deg[i] + 1));
    }
    if (i == 0) row_ptr[n] = N_EDGES;
}

// CSR fill, atomic-free, XCD-class filtered (blockIdx%8 handles one dst range).
// rec = src u16 | fp16(dinv[src]) << 16.
#define BUCKET_BLOCKS 2048
__global__ __launch_bounds__(256) void bucket_kernel(
    const int* __restrict__ src, const int* __restrict__ dst,
    const ushort* __restrict__ rank, const int* __restrict__ row_ptr,
    const float* __restrict__ dinv, unsigned* __restrict__ rec)
{
    int cls = blockIdx.x & 7;
    int blk = blockIdx.x >> 3;                 // 0..255
    int lo = cls * (N_NODES / 8);              // 6250 per class
    int hi = lo + (N_NODES / 8);
    const int CHUNK = (N_EDGES + 255) / 256;   // 3125
    int e0 = blk * CHUNK;
    int e1 = min(e0 + CHUNK, N_EDGES);
    for (int i = e0 + threadIdx.x; i < e1; i += 256) {
        int d = dst[i];
        if (d >= lo && d < hi) {
            int s = src[i];
            unsigned r = (unsigned)(ushort)s |
                         ((unsigned)__half_as_ushort(__float2half_rn(dinv[s])) << 16);
            rec[row_ptr[d] + rank[i]] = r;
        }
    }
}

// W [K][N] fp32 -> Wt [N][K] bf16
__global__ void transpose_w_kernel(const float* __restrict__ W, ushort* __restrict__ Wt,
                                   int K, int N) {
    int i = blockIdx.x * 256 + threadIdx.x;
    if (i < N * K) {
        int n = i / K, k = i % K;
        Wt[i] = f2bf(W[k * N + n]);
    }
}

// C[M,N] = A[M,K] @ B[K,N] (+bias) via bf16 MFMA 16x16x32.
template <bool A_IS_BF16, bool BF16OUT>
__global__ __launch_bounds__(256) void mfma_gemm_kernel(
    const void* __restrict__ Av, const ushort* __restrict__ Bt,
    const float* __restrict__ bias, void* __restrict__ Cv,
    int M, int N, int K)
{
    constexpr int LDK = 40;
    __shared__ ushort As[64 * LDK];
    __shared__ ushort Bs[128 * LDK];
    int tid = threadIdx.x;
    int wave = tid >> 6, lane = tid & 63;
    int quad = lane >> 4, l16 = lane & 15;
    int wm0 = (wave >> 1) * 32, wn0 = (wave & 1) * 64;
    int bm = blockIdx.x * 64, bn = blockIdx.y * 128;

    f32x4 acc[2][4] = {};

    for (int k0 = 0; k0 < K; k0 += 32) {
        {
            int row = tid >> 2, col = (tid & 3) * 8;
            int grow = bm + row;
            if (A_IS_BF16) {
                bf16x8 v = {};
                if (grow < M)
                    v = *(const bf16x8*)((const ushort*)Av + (size_t)grow * K + k0 + col);
                *(bf16x8*)&As[row * LDK + col] = v;
            } else {
                float4 v0 = make_float4(0.f, 0.f, 0.f, 0.f);
                float4 v1 = make_float4(0.f, 0.f, 0.f, 0.f);
                if (grow < M) {
                    const float* ap = (const float*)Av + (size_t)grow * K + k0 + col;
                    v0 = *(const float4*)ap;
                    v1 = *(const float4*)(ap + 4);
                }
                ushort t[8] = {f2bf(v0.x), f2bf(v0.y), f2bf(v0.z), f2bf(v0.w),
                               f2bf(v1.x), f2bf(v1.y), f2bf(v1.z), f2bf(v1.w)};
                *(bf16x8*)&As[row * LDK + col] = *(bf16x8*)t;
            }
        }
        {
            int ch = tid * 2;
            int n = ch >> 2;
            int kk = (ch & 3) * 8;
            const ushort* bp = Bt + (size_t)(bn + n) * K + k0 + kk;
            *(bf16x8*)&Bs[n * LDK + kk]     = *(const bf16x8*)bp;
            *(bf16x8*)&Bs[n * LDK + kk + 8] = *(const bf16x8*)(bp + 8);
        }
        __syncthreads();
        bf16x8 af[2], bfr[4];
        #pragma unroll
        for (int im = 0; im < 2; ++im)
            af[im] = *(bf16x8*)&As[(wm0 + im * 16 + l16) * LDK + quad * 8];
        #pragma unroll
        for (int in = 0; in < 4; ++in)
            bfr[in] = *(bf16x8*)&Bs[(wn0 + in * 16 + l16) * LDK + quad * 8];
        #pragma unroll
        for (int im = 0; im < 2; ++im)
            #pragma unroll
            for (int in = 0; in < 4; ++in)
                acc[im][in] = __builtin_amdgcn_mfma_f32_16x16x32_bf16(
                    af[im], bfr[in], acc[im][in], 0, 0, 0);
        __syncthreads();
    }
    #pragma unroll
    for (int im = 0; im < 2; ++im) {
        #pragma unroll
        for (int in = 0; in < 4; ++in) {
            int col = bn + wn0 + in * 16 + l16;
            float bval = bias ? bias[col] : 0.f;
            #pragma unroll
            for (int r = 0; r < 4; ++r) {
                int grow = bm + wm0 + im * 16 + quad * 4 + r;
                if (grow < M) {
                    float o = acc[im][in][r] + bval;
                    if (BF16OUT)
                        ((ushort*)Cv)[(size_t)grow * N + col] = f2bf(o);
                    else
                        ((float*)Cv)[(size_t)grow * N + col] = o;
                }
            }
        }
    }
}

// convb[d][:] = bf16( di*( sum_in w_s*h[s][:] + di*h[d][:] ) + b_conv )
// wave64 per node. Lanes split in two 32-lane halves; half h processes edges
// begin+h, begin+h+2, ... Each lane owns 4 cols (one dwordx2 per edge).
// Unroll 4 per half -> 8 h-row loads in flight per wave.
__device__ __forceinline__ void acc_edge(float4& acc, unsigned r,
                                         const ushort* __restrict__ hb, int c) {
    unsigned s = r & 0xffffu;
    float w = __half2float(__ushort_as_half((ushort)(r >> 16)));
    uint2 v = *(const uint2*)&hb[(size_t)s * HID + c];
    acc.x += w * __uint_as_float(v.x << 16);
    acc.y += w * __uint_as_float(v.x & 0xffff0000u);
    acc.z += w * __uint_as_float(v.y << 16);
    acc.w += w * __uint_as_float(v.y & 0xffff0000u);
}

__global__ __launch_bounds__(256) void gather_kernel(
    const ushort* __restrict__ hb, const int* __restrict__ row_ptr,
    const unsigned* __restrict__ rec, const float* __restrict__ dinv,
    const float* __restrict__ b_conv, ushort* __restrict__ convb, int n)
{
    int wave = threadIdx.x >> 6;
    int lane = threadIdx.x & 63;
    int d = blockIdx.x * 4 + wave;
    if (d >= n) return;
    int half = lane >> 5;
    int l32 = lane & 31;
    int c = l32 << 2;                 // 4 cols per lane

    float4 acc = make_float4(0.f, 0.f, 0.f, 0.f);
    int begin = row_ptr[d], end = row_ptr[d + 1];
    int e = begin + half;             // this half's edges: e, e+2, e+4, ...
    for (; e + 6 < end; e += 8) {
        unsigned r0 = rec[e];
        unsigned r1 = rec[e + 2];
        unsigned r2 = rec[e + 4];
        unsigned r3 = rec[e + 6];
        acc_edge(acc, r0, hb, c);
        acc_edge(acc, r1, hb, c);
        acc_edge(acc, r2, hb, c);
        acc_edge(acc, r3, hb, c);
    }
    for (; e < end; e += 2) {
        unsigned r0 = rec[e];
        acc_edge(acc, r0, hb, c);
    }
    // combine the two halves (lane bit 5)
    acc.x += __shfl_xor(acc.x, 32);
    acc.y += __shfl_xor(acc.y, 32);
    acc.z += __shfl_xor(acc.z, 32);
    acc.w += __shfl_xor(acc.w, 32);

    if (half == 0) {
        float di = dinv[d];
        uint2 hv = *(const uint2*)&hb[(size_t)d * HID + c];
        acc.x += di * __uint_as_float(hv.x << 16);
        acc.y += di * __uint_as_float(hv.x & 0xffff0000u);
        acc.z += di * __uint_as_float(hv.y << 16);
        acc.w += di * __uint_as_float(hv.y & 0xffff0000u);
        float4 bb = *(const float4*)&b_conv[c];
        float ox = di * acc.x + bb.x;
        float oy = di * acc.y + bb.y;
        float oz = di * acc.z + bb.z;
        float ow = di * acc.w + bb.w;
        uint2 po;
        po.x = ((unsigned)f2bf(oy) << 16) | (unsigned)f2bf(ox);
        po.y = ((unsigned)f2bf(ow) << 16) | (unsigned)f2bf(oz);
        *(uint2*)&convb[(size_t)d * HID + c] = po;
    }
}

extern "C" void kernel_launch(void* const* d_in, const int* in_sizes, int n_in,
                              void* d_out, int out_size, void* d_ws, size_t ws_size,
                              hipStream_t stream) {
    const float* x      = (const float*)d_in[0];
    const int*   ei     = (const int*)d_in[1];
    const float* W_conv = (const float*)d_in[2];
    const float* b_conv = (const float*)d_in[3];
    const float* W_lin  = (const float*)d_in[4];
    const float* b_lin  = (const float*)d_in[5];
    float* out = (float*)d_out;

    char* ws = (char*)d_ws;
    ushort* hb      = (ushort*)(ws + OFF_H);
    ushort* convb   = (ushort*)(ws + OFF_CONV);
    int*    deg     = (int*)(ws + OFF_DEG);
    int*    row_ptr = (int*)(ws + OFF_RP);
    float*  dinv    = (float*)(ws + OFF_DINV);
    ushort* rank    = (ushort*)(ws + OFF_RANK);
    unsigned* rec   = (unsigned*)(ws + OFF_REC);
    int*    bsums   = (int*)(ws + OFF_BSUM);
    ushort* wt_conv = (ushort*)(ws + OFF_WT1);
    ushort* wt_lin  = (ushort*)(ws + OFF_WT2);

    const int* src = ei;
    const int* dst = ei + N_EDGES;

    hipMemsetAsync(deg, 0, 200000, stream);

    deg_kernel<<<(N_EDGES + 255) / 256, 256, 0, stream>>>(dst, deg, rank, N_EDGES);
    scan_blocks_kernel<<<SCAN_BLOCKS, 256, 0, stream>>>(deg, row_ptr, bsums, N_NODES);
    scan_sums_kernel<<<1, 256, 0, stream>>>(bsums, SCAN_BLOCKS);
    finalize_kernel<<<SCAN_BLOCKS, 256, 0, stream>>>(deg, row_ptr, bsums, dinv, N_NODES);
    bucket_kernel<<<BUCKET_BLOCKS, 256, 0, stream>>>(src, dst, rank, row_ptr, dinv, rec);

    transpose_w_kernel<<<(HID * IN_C + 255) / 256, 256, 0, stream>>>(W_conv, wt_conv, IN_C, HID);
    transpose_w_kernel<<<(IN_C * HID + 255) / 256, 256, 0, stream>>>(W_lin, wt_lin, HID, IN_C);

    // h = bf16(x @ W_conv), row-major
    mfma_gemm_kernel<false, true><<<dim3(GEMM_MBLK, HID / 128), 256, 0, stream>>>(
        x, wt_conv, nullptr, hb, N_NODES, HID, IN_C);

    gather_kernel<<<(N_NODES + 3) / 4, 256, 0, stream>>>(
        hb, row_ptr, rec, dinv, b_conv, convb, N_NODES);

    // out = conv @ W_lin + b_lin
    mfma_gemm_kernel<true, false><<<dim3(GEMM_MBLK, IN_C / 128), 256, 0, stream>>>(
        convb, wt_lin, b_lin, out, N_NODES, IN_C, HID);
}